// Round 9
// baseline (188.273 us; speedup 1.0000x reference)
//
#include <hip/hip_runtime.h>

#define NB 64
#define ZDIM 128
#define NCOEF 1025
#define NFR 128
#define COLS 131200          /* NCOEF*NFR */
#define WINSZ 2048
#define HALFW 1024
#define NSAMP 131072
#define IMPN 4096
#define NCHUNK 32            /* chunks of 4 spans */
#define NCK 31               /* checkpoints after frames 2,6,...,122 */

// workspace layout in floats
#define TF_OFF   0
#define TF_SZ    (NB*COLS)
#define TFT_OFF  (TF_OFF + TF_SZ)
#define TFT_SZ   (NB*NFR*NCOEF)
#define CUR_OFF  (TFT_OFF + TFT_SZ)
#define CUR_SZ   (NB*4*NCOEF*2)
#define CK_OFF   (CUR_OFF + CUR_SZ)
#define CK_SZ    (NCK*NB*NCOEF*2)
#define WINT_OFF (CK_OFF + CK_SZ)
#define WINT_SZ  (WINSZ)
#define TW_OFF   (WINT_OFF + WINT_SZ)
#define TW_SZ    (HALFW*2)
#define ZBF_OFF  (TW_OFF + TW_SZ)
#define ZBF_SZ   (NB*ZDIM/2)               /* 8192 bf16 = 4096 floats */

// 2-bit XOR swizzle for the FFT plane: bits[3:2] ^= bits[5:4]
#define PHI(p) ((p) ^ ((((p) >> 4) & 3) << 2))

typedef short bf16x8 __attribute__((ext_vector_type(8)));
typedef float f32x4 __attribute__((ext_vector_type(4)));

__device__ __forceinline__ float2 cmul(float2 a, float2 b) {
  return make_float2(a.x * b.x - a.y * b.y, a.x * b.y + a.y * b.x);
}

// LDS-only workgroup barrier: drains LDS, leaves global loads in flight.
#define WGBAR()                                              \
  do {                                                       \
    asm volatile("s_waitcnt lgkmcnt(0)" ::: "memory");       \
    __builtin_amdgcn_s_barrier();                            \
    asm volatile("" ::: "memory");                           \
  } while (0)

__device__ __forceinline__ short f2bf(float f) {
  unsigned u = __builtin_bit_cast(unsigned, f);
  u += 0x7FFFu + ((u >> 16) & 1u);      // RNE
  return (short)(u >> 16);
}

// ---------------------------------------------------------------- init tables (+ z->bf16)
__global__ __launch_bounds__(256) void init_tables(const float* __restrict__ z,
                                                   float* __restrict__ winT,
                                                   float2* __restrict__ twG,
                                                   short* __restrict__ zbf) {
  int i = blockIdx.x * 256 + threadIdx.x;   // grid 32*256 = 8192
  if (i < WINSZ) {
    winT[i] = 0.5f - 0.5f * cosf((float)(2.0 * 3.14159265358979323846 / 2048.0) * (float)i);
  }
  if (i < HALFW) {
    float ang = (float)(-2.0 * 3.14159265358979323846 / 2048.0) * (float)i;
    float sv, cv;
    sincosf(ang, &sv, &cv);
    twG[i] = make_float2(cv, sv);
  }
  if (i < NB * ZDIM) zbf[i] = f2bf(z[i]);
}

// ---------------------------------------------------------------- MFMA GEMM + squash
// All W loads hoisted (full MLP); z pre-converted to bf16 (direct 16B frag loads).
__global__ __launch_bounds__(256, 2) void tf_gemm_mfma(const short* __restrict__ zbf,
                                                       const float* __restrict__ W,
                                                       const float* __restrict__ bias,
                                                       float* __restrict__ tf) {
  int tid = threadIdx.x;
  int wave = tid >> 6, lane = tid & 63;
  int colw = blockIdx.x * 128 + wave * 32;
  int lr = lane & 15;
  int lk = (lane >> 4) * 8;
  int lq = (lane >> 4) * 4;

  // hoisted W loads: 4 k-steps x 2 n-tiles x 8 k-elems
  float wf[4][2][8];
#pragma unroll
  for (int s = 0; s < 4; ++s)
#pragma unroll
    for (int n = 0; n < 2; ++n) {
      const float* wp = W + (size_t)(s * 32 + lk) * COLS + colw + 16 * n + lr;
#pragma unroll
      for (int j = 0; j < 8; ++j)
        wf[s][n][j] = wp[(size_t)j * COLS];
    }

  // A fragments: single dwordx4 loads of preconverted bf16 z
  bf16x8 afr[4][4];
#pragma unroll
  for (int s = 0; s < 4; ++s)
#pragma unroll
    for (int m = 0; m < 4; ++m)
      afr[s][m] = *reinterpret_cast<const bf16x8*>(zbf + (16 * m + lr) * ZDIM + s * 32 + lk);

  float bv[2];
#pragma unroll
  for (int n = 0; n < 2; ++n) bv[n] = bias[colw + 16 * n + lr];

  f32x4 acc[4][2];
#pragma unroll
  for (int m = 0; m < 4; ++m)
#pragma unroll
    for (int n = 0; n < 2; ++n)
      acc[m][n] = f32x4{bv[n], bv[n], bv[n], bv[n]};

#pragma unroll
  for (int s = 0; s < 4; ++s) {
    bf16x8 bfr[2];
#pragma unroll
    for (int n = 0; n < 2; ++n)
      bfr[n] = bf16x8{f2bf(wf[s][n][0]), f2bf(wf[s][n][1]), f2bf(wf[s][n][2]), f2bf(wf[s][n][3]),
                      f2bf(wf[s][n][4]), f2bf(wf[s][n][5]), f2bf(wf[s][n][6]), f2bf(wf[s][n][7])};
#pragma unroll
    for (int m = 0; m < 4; ++m)
#pragma unroll
      for (int n = 0; n < 2; ++n)
        acc[m][n] = __builtin_amdgcn_mfma_f32_16x16x32_bf16(afr[s][m], bfr[n], acc[m][n], 0, 0, 0);
  }

  const float RESR = (1.0f - 0.02f) * 0.99f;
#pragma unroll
  for (int n = 0; n < 2; ++n) {
    int col = colw + 16 * n + lr;
#pragma unroll
    for (int m = 0; m < 4; ++m) {
      int rowb = 16 * m + lq;
#pragma unroll
      for (int r = 0; r < 4; ++r) {
        float x = acc[m][n][r];
        float sg = 1.0f / (1.0f + __expf(-x));
        tf[(size_t)(rowb + r) * COLS + col] = 0.02f + sg * RESR;
      }
    }
  }
}

// ---------------------------------------------------------------- fwd 2048 FFT (radix-2)
static __device__ __forceinline__ void wg_fft2048(float* ar, float* ai,
                                                  float* br, float* bi,
                                                  const float2* tw,
                                                  float** outr, float** outi) {
  float *xr = ar, *xi = ai, *yr = br, *yi = bi;
  int m = 1;
  for (int s = 0; s < 11; ++s) {
    __syncthreads();
#pragma unroll
    for (int it = 0; it < 4; ++it) {
      int t = (int)threadIdx.x + it * 256;
      int jm = t & ~(m - 1);
      float x0r = xr[t], x0i = xi[t];
      float x1r = xr[t + 1024], x1i = xi[t + 1024];
      float2 w = tw[jm];
      float sr = x0r + x1r, si = x0i + x1i;
      float dr = x0r - x1r, di = x0i - x1i;
      float pr = dr * w.x - di * w.y;
      float pi = dr * w.y + di * w.x;
      yr[t + jm] = sr;      yi[t + jm] = si;
      yr[t + jm + m] = pr;  yi[t + jm + m] = pi;
    }
    float* t0 = xr; xr = yr; yr = t0;
    float* t1 = xi; xi = yi; yi = t1;
    m <<= 1;
  }
  __syncthreads();
  *outr = xr; *outi = xi;
}

__global__ __launch_bounds__(256) void fwd_fft_kernel(const float* __restrict__ imp,
                                                      const float* __restrict__ winT,
                                                      const float2* __restrict__ twG,
                                                      float2* __restrict__ cur) {
  __shared__ float b0r[WINSZ], b0i[WINSZ], b1r[WINSZ], b1i[WINSZ];
  __shared__ float2 tw[HALFW];
  int wg = blockIdx.x;
  int b = wg >> 2, f = wg & 3;
  int tid = threadIdx.x;

  for (int i = tid; i < HALFW; i += 256) tw[i] = twG[i];
  for (int w = tid; w < WINSZ; w += 256) {
    int s = f * HALFW + w;
    float v = (s < IMPN) ? imp[(size_t)b * IMPN + s] * winT[w] : 0.0f;
    b0r[w] = v;
    b0i[w] = 0.0f;
  }
  float *rr, *ri;
  wg_fft2048(b0r, b0i, b1r, b1i, tw, &rr, &ri);
  for (int k = tid; k < NCOEF; k += 256)
    cur[(size_t)wg * NCOEF + k] = make_float2(rr[k], ri[k]);
}

// ---------------------------------------------------------------- recurrence checkpoints + tf transpose
__global__ __launch_bounds__(256) void recur_ck_t(const float* __restrict__ tf,
                                                  const float2* __restrict__ cur,
                                                  float2* __restrict__ ckp,
                                                  float* __restrict__ tft) {
  int id = blockIdx.x * 256 + threadIdx.x;
  if (id >= NB * NCOEF) return;
  int b = id / NCOEF;
  int k = id - b * NCOEF;

  float g = 3.14159265358979323846f * (float)k / 1024.0f;
  float sg, cg;
  sincosf(g, &sg, &cg);
  bool herm = (k == 0) || (k == HALFW);

  const float4* tf4 = (const float4*)(tf + (size_t)b * COLS + (size_t)k * NFR);
  const float2* curb = cur + (size_t)b * 4 * NCOEF + k;
  float* tftb = tft + (size_t)b * NFR * NCOEF + k;

  float pre = 0.0f, pim = 0.0f;
  for (int f4 = 0; f4 < 32; ++f4) {
    float4 tv = tf4[f4];
    float tfs[4] = {tv.x, tv.y, tv.z, tv.w};
#pragma unroll
    for (int u = 0; u < 4; ++u) {
      int f = 4 * f4 + u;
      tftb[(size_t)f * NCOEF] = tfs[u];       // coalesced transpose write
      if (f < 124) {
        float tfv = tfs[u];
        float cr = 0.0f, ci = 0.0f;
        if (f < 4) {
          float2 cv = curb[(size_t)f * NCOEF];
          cr = cv.x; ci = cv.y;
        }
        float ire = herm ? 0.0f : pim;
        float rre = fmaf(pre, cg, ire * sg);
        float rim = -fmaf(pre, sg, ire * cg);
        float sre = (cr + rre) * tfv;
        float sim = (ci + rim) * tfv;
        if ((f & 3) == 2)
          ckp[(size_t)((f - 2) >> 2) * NB * NCOEF + (size_t)b * NCOEF + k] = make_float2(sre, sim);
        pre = sre; pim = sim;
      }
    }
  }
}

// ---------------------------------------------------------------- fused recur + irfft + OLA
// Register DIF radix-4; X-plane P + work-plane Q; 3 raw barriers/frame
// (LDS-only fence so the tft/cur prefetch stays in flight across barriers).
__global__ __launch_bounds__(256, 6) void fused_resyn(const float* __restrict__ tft,
                                                      const float2* __restrict__ cur,
                                                      const float2* __restrict__ ckp,
                                                      const float* __restrict__ winT,
                                                      const float2* __restrict__ twG,
                                                      float* __restrict__ out) {
  __shared__ float2 P[1024];   // X plane (mirror source)
  __shared__ float2 Q[1024];   // butterfly work plane

  int bidx = blockIdx.x;
  int b = bidx >> 5, c = bidx & 31;
  int t = threadIdx.x;

  // ---- recurrence slots: k = t + 256*i (i<4); thread 0 also owns k=1024
  float pre[5], pim[5], cgv[5], sgv[5];
#pragma unroll
  for (int i = 0; i < 5; ++i) {
    if (i == 4) { cgv[4] = -1.0f; sgv[4] = 0.0f; }
    else {
      float2 tv = twG[t + 256 * i];
      cgv[i] = tv.x; sgv[i] = -tv.y;       // cos/sin(pi*k/1024)
    }
    pre[i] = 0.0f; pim[i] = 0.0f;
  }
  if (c > 0) {
    const float2* ck = ckp + ((size_t)(c - 1) * NB + b) * NCOEF;
#pragma unroll
    for (int i = 0; i < 5; ++i) {
      if (i == 4 && t != 0) continue;
      int k = (i == 4) ? 1024 : t + 256 * i;
      float2 v = ck[k];
      pre[i] = v.x; pim[i] = v.y;
    }
  }

  // ---- twiddle preloads
  float2 w1a = twG[2 * t];            float2 w1b = cmul(w1a, w1a); float2 w1c = cmul(w1b, w1a);
  float2 w2a = twG[8 * (t & 63)];     float2 w2b = cmul(w2a, w2a); float2 w2c = cmul(w2b, w2a);
  float2 w3a = twG[32 * (t & 15)];    float2 w3b = cmul(w3a, w3a); float2 w3c = cmul(w3b, w3a);
  float2 w4a = twG[128 * (t & 3)];    float2 w4b = cmul(w4a, w4a); float2 w4c = cmul(w4b, w4a);
  float2 twp0 = twG[t], twp1 = twG[t + 256], twp2 = twG[t + 512], twp3 = twG[t + 768];

  // ---- extract constants (digit-reversed output positions)
  int mb = (t >> 6) + ((t >> 4) & 3) * 4 + ((t >> 2) & 3) * 16 + (t & 3) * 64;
  const float2* win2 = (const float2*)winT;
  float2 wv0 = win2[mb], wv1 = win2[mb + 256], wv2 = win2[mb + 512], wv3 = win2[mb + 768];

  // ---- LDS address constants (swizzled)
  int X0 = PHI(t);
  int B2 = 256 * (t >> 6) + ((t & 63) ^ (((t >> 4) & 3) << 2));
  int b3h = 64 * (t >> 4), i3 = t & 15;
  int b4h = 16 * (t >> 2), i4 = t & 3, c4 = (t >> 2) & 3;
  int p5 = b4h + 4 * ((t & 3) ^ c4);
  int pm0 = PHI((1024 - t) & 1023);
  int pm1 = PHI((1024 - (t + 256)) & 1023);
  int pm2 = PHI((1024 - (t + 512)) & 1023);
  int pm3 = PHI((1024 - (t + 768)) & 1023);

  const float* tftb = tft + (size_t)b * NFR * NCOEF;
  const float2* curb = cur + (size_t)b * 4 * NCOEF;
  const float Cs = 0.5f / 1024.0f;

  int fs = (c == 0) ? 0 : 4 * c - 1;
  int fe = 4 * c + 3;
  float carE0 = 0.0f, carO0 = 0.0f, carE1 = 0.0f, carO1 = 0.0f;

  // ---- prefetch state for frame fs
  float ntf[5];
  float2 ncur[4];
  float2 ncur4;
  {
    const float* tfr = tftb + (size_t)fs * NCOEF;
#pragma unroll
    for (int i = 0; i < 4; ++i) ntf[i] = tfr[t + 256 * i];
    ntf[4] = (t == 0) ? tfr[1024] : 0.0f;
    if (fs < 4) {
#pragma unroll
      for (int i = 0; i < 4; ++i) ncur[i] = curb[(size_t)fs * NCOEF + t + 256 * i];
      ncur4 = (t == 0) ? curb[(size_t)fs * NCOEF + 1024] : make_float2(0.0f, 0.0f);
    } else {
#pragma unroll
      for (int i = 0; i < 4; ++i) ncur[i] = make_float2(0.0f, 0.0f);
      ncur4 = make_float2(0.0f, 0.0f);
    }
  }

  for (int f = fs; f <= fe; ++f) {
    // ---- consume prefetched operands
    float ctf[5];
    float2 ccur[4];
    float2 ccur4 = ncur4;
#pragma unroll
    for (int i = 0; i < 5; ++i) ctf[i] = ntf[i];
#pragma unroll
    for (int i = 0; i < 4; ++i) ccur[i] = ncur[i];

    // ---- issue next frame's loads (hidden under this frame's FFT)
    if (f < fe) {
      int fn = f + 1;
      const float* tfr = tftb + (size_t)fn * NCOEF;
#pragma unroll
      for (int i = 0; i < 4; ++i) ntf[i] = tfr[t + 256 * i];
      ntf[4] = (t == 0) ? tfr[1024] : 0.0f;
      if (fn < 4) {
#pragma unroll
        for (int i = 0; i < 4; ++i) ncur[i] = curb[(size_t)fn * NCOEF + t + 256 * i];
        ncur4 = (t == 0) ? curb[(size_t)fn * NCOEF + 1024] : make_float2(0.0f, 0.0f);
      } else {
#pragma unroll
        for (int i = 0; i < 4; ++i) ncur[i] = make_float2(0.0f, 0.0f);
        ncur4 = make_float2(0.0f, 0.0f);
      }
    }

    // ---- advance recurrence (registers)
    float S[5], I[5];
#pragma unroll
    for (int i = 0; i < 5; ++i) {
      if (i == 4 && t != 0) { S[4] = 0.0f; I[4] = 0.0f; continue; }
      float cr = (i == 4) ? ccur4.x : ccur[i].x;
      float ci = (i == 4) ? ccur4.y : ccur[i].y;
      float rre = fmaf(pre[i], cgv[i], pim[i] * sgv[i]);
      float rim = -fmaf(pre[i], sgv[i], pim[i] * cgv[i]);
      S[i] = (cr + rre) * ctf[i];
      I[i] = (ci + rim) * ctf[i];
      pre[i] = S[i]; pim[i] = I[i];
    }

    // ---- X into P (prev pack reads ordered by prev frame's barriers)
#pragma unroll
    for (int i = 0; i < 4; ++i)
      P[X0 + 256 * i] = make_float2(S[i], I[i]);
    WGBAR();                               // (alpha) X visible

    // ---- pack Z (own X from regs; mirror from P) + stage-1 butterfly
    float2 Z[4];
    {
      float2 xm[4];
      xm[0] = (t == 0) ? make_float2(S[4], 0.0f) : P[pm0];
      xm[1] = P[pm1]; xm[2] = P[pm2]; xm[3] = P[pm3];
      float2 twp[4] = {twp0, twp1, twp2, twp3};
#pragma unroll
      for (int i = 0; i < 4; ++i) {
        float xjr = S[i], xji = I[i];
        float cc = twp[i].x, sn = -twp[i].y;   // e^{+2pi i j/2048}
        float Xer = Cs * (xjr + xm[i].x), Xei = Cs * (xji - xm[i].y);
        float Xpr = Cs * (xjr - xm[i].x), Xpi = Cs * (xji + xm[i].y);
        float Xor_ = Xpr * cc - Xpi * sn;
        float Xoi_ = Xpr * sn + Xpi * cc;
        Z[i] = make_float2(Xer - Xoi_, -(Xei + Xor_));
      }
    }
    float2 y0, y1, y2, y3;
    {
      float2 A = make_float2(Z[0].x + Z[2].x, Z[0].y + Z[2].y);
      float2 Bv = make_float2(Z[0].x - Z[2].x, Z[0].y - Z[2].y);
      float2 Cv = make_float2(Z[1].x + Z[3].x, Z[1].y + Z[3].y);
      float2 D = make_float2(Z[1].x - Z[3].x, Z[1].y - Z[3].y);
      y0 = make_float2(A.x + Cv.x, A.y + Cv.y);
      y1 = cmul(make_float2(Bv.x + D.y, Bv.y - D.x), w1a);
      y2 = cmul(make_float2(A.x - Cv.x, A.y - Cv.y), w1b);
      y3 = cmul(make_float2(Bv.x - D.y, Bv.y + D.x), w1c);
    }
    WGBAR();                               // (beta) prev stage-5 reads of Q done
    P[X0]; // no-op read elision guard (keeps compiler from sinking)
    Q[X0]       = y0;
    Q[X0 + 256] = y1;
    Q[X0 + 512] = y2;
    Q[X0 + 768] = y3;
    WGBAR();                               // (gamma) y visible across waves

    // ---- stage 2 (wave-local, N=256)
    float2 u0 = Q[B2], u1 = Q[B2 + 64], u2 = Q[B2 + 128], u3 = Q[B2 + 192];
    {
      float2 A = make_float2(u0.x + u2.x, u0.y + u2.y);
      float2 Bv = make_float2(u0.x - u2.x, u0.y - u2.y);
      float2 Cv = make_float2(u1.x + u3.x, u1.y + u3.y);
      float2 D = make_float2(u1.x - u3.x, u1.y - u3.y);
      Q[B2]       = make_float2(A.x + Cv.x, A.y + Cv.y);
      Q[B2 + 64]  = cmul(make_float2(Bv.x + D.y, Bv.y - D.x), w2a);
      Q[B2 + 128] = cmul(make_float2(A.x - Cv.x, A.y - Cv.y), w2b);
      Q[B2 + 192] = cmul(make_float2(Bv.x - D.y, Bv.y + D.x), w2c);
    }
    asm volatile("s_waitcnt lgkmcnt(0)" ::: "memory");

    // ---- stage 3 (N=64)
    u0 = Q[b3h + i3];
    u1 = Q[b3h + 16 + (i3 ^ 4)];
    u2 = Q[b3h + 32 + (i3 ^ 8)];
    u3 = Q[b3h + 48 + (i3 ^ 12)];
    {
      float2 A = make_float2(u0.x + u2.x, u0.y + u2.y);
      float2 Bv = make_float2(u0.x - u2.x, u0.y - u2.y);
      float2 Cv = make_float2(u1.x + u3.x, u1.y + u3.y);
      float2 D = make_float2(u1.x - u3.x, u1.y - u3.y);
      Q[b3h + i3]             = make_float2(A.x + Cv.x, A.y + Cv.y);
      Q[b3h + 16 + (i3 ^ 4)]  = cmul(make_float2(Bv.x + D.y, Bv.y - D.x), w3a);
      Q[b3h + 32 + (i3 ^ 8)]  = cmul(make_float2(A.x - Cv.x, A.y - Cv.y), w3b);
      Q[b3h + 48 + (i3 ^ 12)] = cmul(make_float2(Bv.x - D.y, Bv.y + D.x), w3c);
    }
    asm volatile("s_waitcnt lgkmcnt(0)" ::: "memory");

    // ---- stage 4 (N=16)
    u0 = Q[b4h + 4 * (0 ^ c4) + i4];
    u1 = Q[b4h + 4 * (1 ^ c4) + i4];
    u2 = Q[b4h + 4 * (2 ^ c4) + i4];
    u3 = Q[b4h + 4 * (3 ^ c4) + i4];
    {
      float2 A = make_float2(u0.x + u2.x, u0.y + u2.y);
      float2 Bv = make_float2(u0.x - u2.x, u0.y - u2.y);
      float2 Cv = make_float2(u1.x + u3.x, u1.y + u3.y);
      float2 D = make_float2(u1.x - u3.x, u1.y - u3.y);
      Q[b4h + 4 * (0 ^ c4) + i4] = make_float2(A.x + Cv.x, A.y + Cv.y);
      Q[b4h + 4 * (1 ^ c4) + i4] = cmul(make_float2(Bv.x + D.y, Bv.y - D.x), w4a);
      Q[b4h + 4 * (2 ^ c4) + i4] = cmul(make_float2(A.x - Cv.x, A.y - Cv.y), w4b);
      Q[b4h + 4 * (3 ^ c4) + i4] = cmul(make_float2(Bv.x - D.y, Bv.y + D.x), w4c);
    }
    asm volatile("s_waitcnt lgkmcnt(0)" ::: "memory");

    // ---- stage 5 (N=4) -> regs
    float4 q01 = *reinterpret_cast<const float4*>(&Q[p5]);
    float4 q23 = *reinterpret_cast<const float4*>(&Q[p5 + 2]);
    float2 z0, z1, z2, z3;
    {
      float2 a = make_float2(q01.x, q01.y), bq = make_float2(q01.z, q01.w);
      float2 cq = make_float2(q23.x, q23.y), d = make_float2(q23.z, q23.w);
      float2 A = make_float2(a.x + cq.x, a.y + cq.y);
      float2 Bv = make_float2(a.x - cq.x, a.y - cq.y);
      float2 Cv = make_float2(bq.x + d.x, bq.y + d.y);
      float2 D = make_float2(bq.x - d.x, bq.y - d.y);
      z0 = make_float2(A.x + Cv.x, A.y + Cv.y);
      z1 = make_float2(Bv.x + D.y, Bv.y - D.x);
      z2 = make_float2(A.x - Cv.x, A.y - Cv.y);
      z3 = make_float2(Bv.x - D.y, Bv.y + D.x);
    }

    // ---- extract: x[2m]=Re z[m], x[2m+1]=-Im z[m]; m = mb + 256q
    float e0 = z0.x * wv0.x, o0 = -z0.y * wv0.y;
    float e1 = z1.x * wv1.x, o1 = -z1.y * wv1.y;
    float e2 = z2.x * wv2.x, o2 = -z2.y * wv2.y;
    float e3 = z3.x * wv3.x, o3 = -z3.y * wv3.y;
    if (f >= 4 * c) {
      float2* ob2 = (float2*)(out + (size_t)b * NSAMP + (size_t)f * 1024);
      ob2[mb]       = make_float2(e0 + carE0, o0 + carO0);
      ob2[mb + 256] = make_float2(e1 + carE1, o1 + carO1);
    }
    carE0 = e2; carO0 = o2;
    carE1 = e3; carO1 = o3;
  }
}

// ---------------------------------------------------------------- launch
extern "C" void kernel_launch(void* const* d_in, const int* in_sizes, int n_in,
                              void* d_out, int out_size, void* d_ws, size_t ws_size,
                              hipStream_t stream) {
  const float* z    = (const float*)d_in[0];
  const float* imp  = (const float*)d_in[1];
  const float* W    = (const float*)d_in[2];
  const float* bias = (const float*)d_in[3];

  float* ws = (float*)d_ws;
  float*  tf   = ws + TF_OFF;
  float*  tft  = ws + TFT_OFF;
  float2* cur  = (float2*)(ws + CUR_OFF);
  float2* ckp  = (float2*)(ws + CK_OFF);
  float*  winT = ws + WINT_OFF;
  float2* twG  = (float2*)(ws + TW_OFF);
  short*  zbf  = (short*)(ws + ZBF_OFF);
  float*  out  = (float*)d_out;

  init_tables<<<32, 256, 0, stream>>>(z, winT, twG, zbf);
  tf_gemm_mfma<<<COLS / 128, 256, 0, stream>>>(zbf, W, bias, tf);
  fwd_fft_kernel<<<NB * 4, 256, 0, stream>>>(imp, winT, twG, cur);
  recur_ck_t<<<(NB * NCOEF + 255) / 256, 256, 0, stream>>>(tf, cur, ckp, tft);
  fused_resyn<<<NB * NCHUNK, 256, 0, stream>>>(tft, cur, ckp, winT, twG, out);
}

// Round 10
// 93.971 us; speedup vs baseline: 2.0035x; 2.0035x over previous
//
#include <hip/hip_runtime.h>

#define NB 64
#define ZDIM 128
#define NCOEF 1025
#define NFR 128
#define COLS 131200          /* NCOEF*NFR */
#define WINSZ 2048
#define HALFW 1024
#define NSAMP 131072
#define IMPN 4096
#define NCHUNK 32            /* chunks of 4 spans */
#define NCK 31               /* checkpoints after frames 2,6,...,122 */

// workspace layout in floats
#define TF_OFF   0
#define TF_SZ    (NB*COLS)
#define TFT_OFF  (TF_OFF + TF_SZ)
#define TFT_SZ   (NB*NFR*NCOEF)
#define CUR_OFF  (TFT_OFF + TFT_SZ)
#define CUR_SZ   (NB*4*NCOEF*2)
#define CK_OFF   (CUR_OFF + CUR_SZ)
#define CK_SZ    (NCK*NB*NCOEF*2)
#define WINT_OFF (CK_OFF + CK_SZ)
#define WINT_SZ  (WINSZ)
#define TW_OFF   (WINT_OFF + WINT_SZ)
#define TW_SZ    (HALFW*2)
#define ZBF_OFF  (TW_OFF + TW_SZ)
#define ZBF_SZ   (NB*ZDIM/2)

// 2-bit XOR swizzle for the FFT plane: bits[3:2] ^= bits[5:4]
#define PHI(p) ((p) ^ ((((p) >> 4) & 3) << 2))

typedef short bf16x8 __attribute__((ext_vector_type(8)));
typedef float f32x4 __attribute__((ext_vector_type(4)));

__device__ __forceinline__ float2 cmul(float2 a, float2 b) {
  return make_float2(a.x * b.x - a.y * b.y, a.x * b.y + a.y * b.x);
}

// LDS-only workgroup barrier: drains LDS, leaves global loads in flight.
#define WGBAR()                                              \
  do {                                                       \
    asm volatile("s_waitcnt lgkmcnt(0)" ::: "memory");       \
    __builtin_amdgcn_s_barrier();                            \
    asm volatile("" ::: "memory");                           \
  } while (0)

__device__ __forceinline__ short f2bf(float f) {
  unsigned u = __builtin_bit_cast(unsigned, f);
  u += 0x7FFFu + ((u >> 16) & 1u);      // RNE
  return (short)(u >> 16);
}

// ---------------------------------------------------------------- init tables (+ z->bf16)
__global__ __launch_bounds__(256) void init_tables(const float* __restrict__ z,
                                                   float* __restrict__ winT,
                                                   float2* __restrict__ twG,
                                                   short* __restrict__ zbf) {
  int i = blockIdx.x * 256 + threadIdx.x;   // grid 32*256 = 8192
  if (i < WINSZ) {
    winT[i] = 0.5f - 0.5f * cosf((float)(2.0 * 3.14159265358979323846 / 2048.0) * (float)i);
  }
  if (i < HALFW) {
    float ang = (float)(-2.0 * 3.14159265358979323846 / 2048.0) * (float)i;
    float sv, cv;
    sincosf(ang, &sv, &cv);
    twG[i] = make_float2(cv, sv);
  }
  if (i < NB * ZDIM) zbf[i] = f2bf(z[i]);
}

// ---------------------------------------------------------------- MFMA GEMM + squash
__global__ __launch_bounds__(256, 2) void tf_gemm_mfma(const short* __restrict__ zbf,
                                                       const float* __restrict__ W,
                                                       const float* __restrict__ bias,
                                                       float* __restrict__ tf) {
  int tid = threadIdx.x;
  int wave = tid >> 6, lane = tid & 63;
  int colw = blockIdx.x * 128 + wave * 32;
  int lr = lane & 15;
  int lk = (lane >> 4) * 8;
  int lq = (lane >> 4) * 4;

  // hoisted W loads: 4 k-steps x 2 n-tiles x 8 k-elems
  float wf[4][2][8];
#pragma unroll
  for (int s = 0; s < 4; ++s)
#pragma unroll
    for (int n = 0; n < 2; ++n) {
      const float* wp = W + (size_t)(s * 32 + lk) * COLS + colw + 16 * n + lr;
#pragma unroll
      for (int j = 0; j < 8; ++j)
        wf[s][n][j] = wp[(size_t)j * COLS];
    }

  // A fragments: single dwordx4 loads of preconverted bf16 z
  bf16x8 afr[4][4];
#pragma unroll
  for (int s = 0; s < 4; ++s)
#pragma unroll
    for (int m = 0; m < 4; ++m)
      afr[s][m] = *reinterpret_cast<const bf16x8*>(zbf + (16 * m + lr) * ZDIM + s * 32 + lk);

  float bv[2];
#pragma unroll
  for (int n = 0; n < 2; ++n) bv[n] = bias[colw + 16 * n + lr];

  f32x4 acc[4][2];
#pragma unroll
  for (int m = 0; m < 4; ++m)
#pragma unroll
    for (int n = 0; n < 2; ++n)
      acc[m][n] = f32x4{bv[n], bv[n], bv[n], bv[n]};

#pragma unroll
  for (int s = 0; s < 4; ++s) {
    bf16x8 bfr[2];
#pragma unroll
    for (int n = 0; n < 2; ++n)
      bfr[n] = bf16x8{f2bf(wf[s][n][0]), f2bf(wf[s][n][1]), f2bf(wf[s][n][2]), f2bf(wf[s][n][3]),
                      f2bf(wf[s][n][4]), f2bf(wf[s][n][5]), f2bf(wf[s][n][6]), f2bf(wf[s][n][7])};
#pragma unroll
    for (int m = 0; m < 4; ++m)
#pragma unroll
      for (int n = 0; n < 2; ++n)
        acc[m][n] = __builtin_amdgcn_mfma_f32_16x16x32_bf16(afr[s][m], bfr[n], acc[m][n], 0, 0, 0);
  }

  const float RESR = (1.0f - 0.02f) * 0.99f;
#pragma unroll
  for (int n = 0; n < 2; ++n) {
    int col = colw + 16 * n + lr;
#pragma unroll
    for (int m = 0; m < 4; ++m) {
      int rowb = 16 * m + lq;
#pragma unroll
      for (int r = 0; r < 4; ++r) {
        float x = acc[m][n][r];
        float sg = 1.0f / (1.0f + __expf(-x));
        tf[(size_t)(rowb + r) * COLS + col] = 0.02f + sg * RESR;
      }
    }
  }
}

// ---------------------------------------------------------------- fwd 2048 FFT (radix-2)
static __device__ __forceinline__ void wg_fft2048(float* ar, float* ai,
                                                  float* br, float* bi,
                                                  const float2* tw,
                                                  float** outr, float** outi) {
  float *xr = ar, *xi = ai, *yr = br, *yi = bi;
  int m = 1;
  for (int s = 0; s < 11; ++s) {
    __syncthreads();
#pragma unroll
    for (int it = 0; it < 4; ++it) {
      int t = (int)threadIdx.x + it * 256;
      int jm = t & ~(m - 1);
      float x0r = xr[t], x0i = xi[t];
      float x1r = xr[t + 1024], x1i = xi[t + 1024];
      float2 w = tw[jm];
      float sr = x0r + x1r, si = x0i + x1i;
      float dr = x0r - x1r, di = x0i - x1i;
      float pr = dr * w.x - di * w.y;
      float pi = dr * w.y + di * w.x;
      yr[t + jm] = sr;      yi[t + jm] = si;
      yr[t + jm + m] = pr;  yi[t + jm + m] = pi;
    }
    float* t0 = xr; xr = yr; yr = t0;
    float* t1 = xi; xi = yi; yi = t1;
    m <<= 1;
  }
  __syncthreads();
  *outr = xr; *outi = xi;
}

__global__ __launch_bounds__(256) void fwd_fft_kernel(const float* __restrict__ imp,
                                                      const float* __restrict__ winT,
                                                      const float2* __restrict__ twG,
                                                      float2* __restrict__ cur) {
  __shared__ float b0r[WINSZ], b0i[WINSZ], b1r[WINSZ], b1i[WINSZ];
  __shared__ float2 tw[HALFW];
  int wg = blockIdx.x;
  int b = wg >> 2, f = wg & 3;
  int tid = threadIdx.x;

  for (int i = tid; i < HALFW; i += 256) tw[i] = twG[i];
  for (int w = tid; w < WINSZ; w += 256) {
    int s = f * HALFW + w;
    float v = (s < IMPN) ? imp[(size_t)b * IMPN + s] * winT[w] : 0.0f;
    b0r[w] = v;
    b0i[w] = 0.0f;
  }
  float *rr, *ri;
  wg_fft2048(b0r, b0i, b1r, b1i, tw, &rr, &ri);
  for (int k = tid; k < NCOEF; k += 256)
    cur[(size_t)wg * NCOEF + k] = make_float2(rr[k], ri[k]);
}

// ---------------------------------------------------------------- recurrence checkpoints + tf transpose
__global__ __launch_bounds__(256) void recur_ck_t(const float* __restrict__ tf,
                                                  const float2* __restrict__ cur,
                                                  float2* __restrict__ ckp,
                                                  float* __restrict__ tft) {
  int id = blockIdx.x * 256 + threadIdx.x;
  if (id >= NB * NCOEF) return;
  int b = id / NCOEF;
  int k = id - b * NCOEF;

  float g = 3.14159265358979323846f * (float)k / 1024.0f;
  float sg, cg;
  sincosf(g, &sg, &cg);
  bool herm = (k == 0) || (k == HALFW);

  const float4* tf4 = (const float4*)(tf + (size_t)b * COLS + (size_t)k * NFR);
  const float2* curb = cur + (size_t)b * 4 * NCOEF + k;
  float* tftb = tft + (size_t)b * NFR * NCOEF + k;

  float pre = 0.0f, pim = 0.0f;
  for (int f4 = 0; f4 < 32; ++f4) {
    float4 tv = tf4[f4];
    float tfs[4] = {tv.x, tv.y, tv.z, tv.w};
#pragma unroll
    for (int u = 0; u < 4; ++u) {
      int f = 4 * f4 + u;
      tftb[(size_t)f * NCOEF] = tfs[u];       // coalesced transpose write
      if (f < 124) {
        float tfv = tfs[u];
        float cr = 0.0f, ci = 0.0f;
        if (f < 4) {
          float2 cv = curb[(size_t)f * NCOEF];
          cr = cv.x; ci = cv.y;
        }
        float ire = herm ? 0.0f : pim;
        float rre = fmaf(pre, cg, ire * sg);
        float rim = -fmaf(pre, sg, ire * cg);
        float sre = (cr + rre) * tfv;
        float sim = (ci + rim) * tfv;
        if ((f & 3) == 2)
          ckp[(size_t)((f - 2) >> 2) * NB * NCOEF + (size_t)b * NCOEF + k] = make_float2(sre, sim);
        pre = sre; pim = sim;
      }
    }
  }
}

// ---------------------------------------------------------------- fused recur + irfft + OLA
// Register DIF radix-4; X-plane P + work-plane Q; 3 LDS-only barriers/frame.
// No VGPR cap (round-9's (256,6) cap caused spill-to-scratch: 258MB fetch).
__global__ __launch_bounds__(256) void fused_resyn(const float* __restrict__ tft,
                                                   const float2* __restrict__ cur,
                                                   const float2* __restrict__ ckp,
                                                   const float* __restrict__ winT,
                                                   const float2* __restrict__ twG,
                                                   float* __restrict__ out) {
  __shared__ float2 P[1024];   // X plane (mirror source)
  __shared__ float2 Q[1024];   // butterfly work plane

  int bidx = blockIdx.x;
  int b = bidx >> 5, c = bidx & 31;
  int t = threadIdx.x;

  // ---- recurrence slots: k = t + 256*i (i<4); thread 0 also owns k=1024
  float pre[5], pim[5], cgv[5], sgv[5];
#pragma unroll
  for (int i = 0; i < 5; ++i) {
    if (i == 4) { cgv[4] = -1.0f; sgv[4] = 0.0f; }
    else {
      float2 tv = twG[t + 256 * i];
      cgv[i] = tv.x; sgv[i] = -tv.y;       // cos/sin(pi*k/1024)
    }
    pre[i] = 0.0f; pim[i] = 0.0f;
  }
  if (c > 0) {
    const float2* ck = ckp + ((size_t)(c - 1) * NB + b) * NCOEF;
#pragma unroll
    for (int i = 0; i < 5; ++i) {
      if (i == 4 && t != 0) continue;
      int k = (i == 4) ? 1024 : t + 256 * i;
      float2 v = ck[k];
      pre[i] = v.x; pim[i] = v.y;
    }
  }

  // ---- twiddle preloads
  float2 w1a = twG[2 * t];            float2 w1b = cmul(w1a, w1a); float2 w1c = cmul(w1b, w1a);
  float2 w2a = twG[8 * (t & 63)];     float2 w2b = cmul(w2a, w2a); float2 w2c = cmul(w2b, w2a);
  float2 w3a = twG[32 * (t & 15)];    float2 w3b = cmul(w3a, w3a); float2 w3c = cmul(w3b, w3a);
  float2 w4a = twG[128 * (t & 3)];    float2 w4b = cmul(w4a, w4a); float2 w4c = cmul(w4b, w4a);
  float2 twp0 = twG[t], twp1 = twG[t + 256], twp2 = twG[t + 512], twp3 = twG[t + 768];

  // ---- extract constants (digit-reversed output positions)
  int mb = (t >> 6) + ((t >> 4) & 3) * 4 + ((t >> 2) & 3) * 16 + (t & 3) * 64;
  const float2* win2 = (const float2*)winT;
  float2 wv0 = win2[mb], wv1 = win2[mb + 256], wv2 = win2[mb + 512], wv3 = win2[mb + 768];

  // ---- LDS address constants (swizzled)
  int X0 = PHI(t);
  int B2 = 256 * (t >> 6) + ((t & 63) ^ (((t >> 4) & 3) << 2));
  int b3h = 64 * (t >> 4), i3 = t & 15;
  int b4h = 16 * (t >> 2), i4 = t & 3, c4 = (t >> 2) & 3;
  int p5 = b4h + 4 * ((t & 3) ^ c4);
  int pm0 = PHI((1024 - t) & 1023);
  int pm1 = PHI((1024 - (t + 256)) & 1023);
  int pm2 = PHI((1024 - (t + 512)) & 1023);
  int pm3 = PHI((1024 - (t + 768)) & 1023);

  const float* tftb = tft + (size_t)b * NFR * NCOEF;
  const float2* curb = cur + (size_t)b * 4 * NCOEF;
  const float Cs = 0.5f / 1024.0f;

  int fs = (c == 0) ? 0 : 4 * c - 1;
  int fe = 4 * c + 3;
  float carE0 = 0.0f, carO0 = 0.0f, carE1 = 0.0f, carO1 = 0.0f;

  // ---- tf prefetch for frame fs (cur read inline; only c==0 has f<4)
  float ntf[5];
  {
    const float* tfr = tftb + (size_t)fs * NCOEF;
#pragma unroll
    for (int i = 0; i < 4; ++i) ntf[i] = tfr[t + 256 * i];
    ntf[4] = (t == 0) ? tfr[1024] : 0.0f;
  }

  for (int f = fs; f <= fe; ++f) {
    float ctf[5];
#pragma unroll
    for (int i = 0; i < 5; ++i) ctf[i] = ntf[i];

    // ---- issue next frame's tf loads (hide under this frame's FFT)
    if (f < fe) {
      const float* tfr = tftb + (size_t)(f + 1) * NCOEF;
#pragma unroll
      for (int i = 0; i < 4; ++i) ntf[i] = tfr[t + 256 * i];
      ntf[4] = (t == 0) ? tfr[1024] : 0.0f;
    }

    // ---- advance recurrence (registers)
    float S[5], I[5];
#pragma unroll
    for (int i = 0; i < 5; ++i) {
      if (i == 4 && t != 0) { S[4] = 0.0f; I[4] = 0.0f; continue; }
      float cr = 0.0f, ci = 0.0f;
      if (f < 4) {
        int k = (i == 4) ? 1024 : t + 256 * i;
        float2 cv = curb[(size_t)f * NCOEF + k];
        cr = cv.x; ci = cv.y;
      }
      float rre = fmaf(pre[i], cgv[i], pim[i] * sgv[i]);
      float rim = -fmaf(pre[i], sgv[i], pim[i] * cgv[i]);
      S[i] = (cr + rre) * ctf[i];
      I[i] = (ci + rim) * ctf[i];
      pre[i] = S[i]; pim[i] = I[i];
    }

    // ---- X into P
#pragma unroll
    for (int i = 0; i < 4; ++i)
      P[X0 + 256 * i] = make_float2(S[i], I[i]);
    WGBAR();                               // (alpha) X visible

    // ---- pack Z (own X from regs; mirror from P) + stage-1 butterfly
    float2 Z[4];
    {
      float2 xm[4];
      xm[0] = (t == 0) ? make_float2(S[4], 0.0f) : P[pm0];
      xm[1] = P[pm1]; xm[2] = P[pm2]; xm[3] = P[pm3];
      float2 twp[4] = {twp0, twp1, twp2, twp3};
#pragma unroll
      for (int i = 0; i < 4; ++i) {
        float xjr = S[i], xji = I[i];
        float cc = twp[i].x, sn = -twp[i].y;   // e^{+2pi i j/2048}
        float Xer = Cs * (xjr + xm[i].x), Xei = Cs * (xji - xm[i].y);
        float Xpr = Cs * (xjr - xm[i].x), Xpi = Cs * (xji + xm[i].y);
        float Xor_ = Xpr * cc - Xpi * sn;
        float Xoi_ = Xpr * sn + Xpi * cc;
        Z[i] = make_float2(Xer - Xoi_, -(Xei + Xor_));
      }
    }
    float2 y0, y1, y2, y3;
    {
      float2 A = make_float2(Z[0].x + Z[2].x, Z[0].y + Z[2].y);
      float2 Bv = make_float2(Z[0].x - Z[2].x, Z[0].y - Z[2].y);
      float2 Cv = make_float2(Z[1].x + Z[3].x, Z[1].y + Z[3].y);
      float2 D = make_float2(Z[1].x - Z[3].x, Z[1].y - Z[3].y);
      y0 = make_float2(A.x + Cv.x, A.y + Cv.y);
      y1 = cmul(make_float2(Bv.x + D.y, Bv.y - D.x), w1a);
      y2 = cmul(make_float2(A.x - Cv.x, A.y - Cv.y), w1b);
      y3 = cmul(make_float2(Bv.x - D.y, Bv.y + D.x), w1c);
    }
    WGBAR();                               // (beta) prev stage-5 reads of Q done
    Q[X0]       = y0;
    Q[X0 + 256] = y1;
    Q[X0 + 512] = y2;
    Q[X0 + 768] = y3;
    WGBAR();                               // (gamma) y visible across waves

    // ---- stage 2 (wave-local, N=256)
    float2 u0 = Q[B2], u1 = Q[B2 + 64], u2 = Q[B2 + 128], u3 = Q[B2 + 192];
    {
      float2 A = make_float2(u0.x + u2.x, u0.y + u2.y);
      float2 Bv = make_float2(u0.x - u2.x, u0.y - u2.y);
      float2 Cv = make_float2(u1.x + u3.x, u1.y + u3.y);
      float2 D = make_float2(u1.x - u3.x, u1.y - u3.y);
      Q[B2]       = make_float2(A.x + Cv.x, A.y + Cv.y);
      Q[B2 + 64]  = cmul(make_float2(Bv.x + D.y, Bv.y - D.x), w2a);
      Q[B2 + 128] = cmul(make_float2(A.x - Cv.x, A.y - Cv.y), w2b);
      Q[B2 + 192] = cmul(make_float2(Bv.x - D.y, Bv.y + D.x), w2c);
    }
    asm volatile("s_waitcnt lgkmcnt(0)" ::: "memory");

    // ---- stage 3 (N=64)
    u0 = Q[b3h + i3];
    u1 = Q[b3h + 16 + (i3 ^ 4)];
    u2 = Q[b3h + 32 + (i3 ^ 8)];
    u3 = Q[b3h + 48 + (i3 ^ 12)];
    {
      float2 A = make_float2(u0.x + u2.x, u0.y + u2.y);
      float2 Bv = make_float2(u0.x - u2.x, u0.y - u2.y);
      float2 Cv = make_float2(u1.x + u3.x, u1.y + u3.y);
      float2 D = make_float2(u1.x - u3.x, u1.y - u3.y);
      Q[b3h + i3]             = make_float2(A.x + Cv.x, A.y + Cv.y);
      Q[b3h + 16 + (i3 ^ 4)]  = cmul(make_float2(Bv.x + D.y, Bv.y - D.x), w3a);
      Q[b3h + 32 + (i3 ^ 8)]  = cmul(make_float2(A.x - Cv.x, A.y - Cv.y), w3b);
      Q[b3h + 48 + (i3 ^ 12)] = cmul(make_float2(Bv.x - D.y, Bv.y + D.x), w3c);
    }
    asm volatile("s_waitcnt lgkmcnt(0)" ::: "memory");

    // ---- stage 4 (N=16)
    u0 = Q[b4h + 4 * (0 ^ c4) + i4];
    u1 = Q[b4h + 4 * (1 ^ c4) + i4];
    u2 = Q[b4h + 4 * (2 ^ c4) + i4];
    u3 = Q[b4h + 4 * (3 ^ c4) + i4];
    {
      float2 A = make_float2(u0.x + u2.x, u0.y + u2.y);
      float2 Bv = make_float2(u0.x - u2.x, u0.y - u2.y);
      float2 Cv = make_float2(u1.x + u3.x, u1.y + u3.y);
      float2 D = make_float2(u1.x - u3.x, u1.y - u3.y);
      Q[b4h + 4 * (0 ^ c4) + i4] = make_float2(A.x + Cv.x, A.y + Cv.y);
      Q[b4h + 4 * (1 ^ c4) + i4] = cmul(make_float2(Bv.x + D.y, Bv.y - D.x), w4a);
      Q[b4h + 4 * (2 ^ c4) + i4] = cmul(make_float2(A.x - Cv.x, A.y - Cv.y), w4b);
      Q[b4h + 4 * (3 ^ c4) + i4] = cmul(make_float2(Bv.x - D.y, Bv.y + D.x), w4c);
    }
    asm volatile("s_waitcnt lgkmcnt(0)" ::: "memory");

    // ---- stage 5 (N=4) -> regs
    float4 q01 = *reinterpret_cast<const float4*>(&Q[p5]);
    float4 q23 = *reinterpret_cast<const float4*>(&Q[p5 + 2]);
    float2 z0, z1, z2, z3;
    {
      float2 a = make_float2(q01.x, q01.y), bq = make_float2(q01.z, q01.w);
      float2 cq = make_float2(q23.x, q23.y), d = make_float2(q23.z, q23.w);
      float2 A = make_float2(a.x + cq.x, a.y + cq.y);
      float2 Bv = make_float2(a.x - cq.x, a.y - cq.y);
      float2 Cv = make_float2(bq.x + d.x, bq.y + d.y);
      float2 D = make_float2(bq.x - d.x, bq.y - d.y);
      z0 = make_float2(A.x + Cv.x, A.y + Cv.y);
      z1 = make_float2(Bv.x + D.y, Bv.y - D.x);
      z2 = make_float2(A.x - Cv.x, A.y - Cv.y);
      z3 = make_float2(Bv.x - D.y, Bv.y + D.x);
    }

    // ---- extract: x[2m]=Re z[m], x[2m+1]=-Im z[m]; m = mb + 256q
    float e0 = z0.x * wv0.x, o0 = -z0.y * wv0.y;
    float e1 = z1.x * wv1.x, o1 = -z1.y * wv1.y;
    float e2 = z2.x * wv2.x, o2 = -z2.y * wv2.y;
    float e3 = z3.x * wv3.x, o3 = -z3.y * wv3.y;
    if (f >= 4 * c) {
      float2* ob2 = (float2*)(out + (size_t)b * NSAMP + (size_t)f * 1024);
      ob2[mb]       = make_float2(e0 + carE0, o0 + carO0);
      ob2[mb + 256] = make_float2(e1 + carE1, o1 + carO1);
    }
    carE0 = e2; carO0 = o2;
    carE1 = e3; carO1 = o3;
  }
}

// ---------------------------------------------------------------- launch
extern "C" void kernel_launch(void* const* d_in, const int* in_sizes, int n_in,
                              void* d_out, int out_size, void* d_ws, size_t ws_size,
                              hipStream_t stream) {
  const float* z    = (const float*)d_in[0];
  const float* imp  = (const float*)d_in[1];
  const float* W    = (const float*)d_in[2];
  const float* bias = (const float*)d_in[3];

  float* ws = (float*)d_ws;
  float*  tf   = ws + TF_OFF;
  float*  tft  = ws + TFT_OFF;
  float2* cur  = (float2*)(ws + CUR_OFF);
  float2* ckp  = (float2*)(ws + CK_OFF);
  float*  winT = ws + WINT_OFF;
  float2* twG  = (float2*)(ws + TW_OFF);
  short*  zbf  = (short*)(ws + ZBF_OFF);
  float*  out  = (float*)d_out;

  init_tables<<<32, 256, 0, stream>>>(z, winT, twG, zbf);
  tf_gemm_mfma<<<COLS / 128, 256, 0, stream>>>(zbf, W, bias, tf);
  fwd_fft_kernel<<<NB * 4, 256, 0, stream>>>(imp, winT, twG, cur);
  recur_ck_t<<<(NB * NCOEF + 255) / 256, 256, 0, stream>>>(tf, cur, ckp, tft);
  fused_resyn<<<NB * NCHUNK, 256, 0, stream>>>(tft, cur, ckp, winT, twG, out);
}